// Round 1
// baseline (2385.066 us; speedup 1.0000x reference)
//
#include <hip/hip_runtime.h>

#define TT 2048
#define NB 512
#define HH 64

__device__ __forceinline__ float fsig(float x) {
    return 1.0f / (1.0f + __expf(-x));
}
__device__ __forceinline__ float ftanh(float x) {
    return 2.0f / (1.0f + __expf(-2.0f * x)) - 1.0f;
}

// One block (4 waves) per batch element.
// wave g = gate g (TF order: i, j, f, o); lane u = hidden unit u.
// W1 column (65 floats) lives in registers per lane.
// Layer 2 runs 1 step behind layer 1 (parity-double-buffered partials),
// scalar (c2,h2) chain 2 steps behind — off the h1 critical path.
__global__ __launch_bounds__(256, 2)
void lstm2_kernel(const float* __restrict__ x,
                  const float* __restrict__ W1,
                  const float* __restrict__ b1,
                  const float* __restrict__ W2,
                  const float* __restrict__ b2,
                  float* __restrict__ out)
{
    __shared__ __align__(16) float xall[TT];   // whole input row: 8 KB
    __shared__ __align__(16) float h1s[HH];    // h1(t-1) broadcast buffer
    __shared__ float gbuf[4][HH];              // per-gate nonlin outputs
    __shared__ float zp[2][4];                 // layer-2 partials, parity dbuf

    const int b    = blockIdx.x;
    const int tid  = threadIdx.x;
    const int wave = tid >> 6;
    const int lane = tid & 63;

    for (int i = tid; i < TT; i += 256) xall[i] = x[b * TT + i];

    // W1 is (65, 256) row-major; this lane's column = wave*64 + lane
    const int col = (wave << 6) + lane;
    float w[65];
#pragma unroll
    for (int r = 0; r < 65; ++r) w[r] = W1[r * 256 + col];
    const float bias = b1[col];
    // W2 is (65, 4) row-major; lane m holds W2[m][g] for its wave's gate
    const float w2g = W2[lane * 4 + wave];

    float w2h0=0.f, w2h1=0.f, w2h2=0.f, w2h3=0.f;
    float b20=0.f, b21=0.f, b22=0.f, b23=0.f;
    if (wave == 3 && lane == 0) {       // scalar-chain owner
        w2h0 = W2[256]; w2h1 = W2[257]; w2h2 = W2[258]; w2h3 = W2[259];
        b20 = b2[0]; b21 = b2[1]; b22 = b2[2]; b23 = b2[3];
    }

    float c1 = 0.0f;                 // wave0, lane u: cell state of unit u
    float c2 = 0.0f, h2 = 0.0f;      // wave3 lane0: layer-2 scalar state

    if (tid < HH) h1s[tid] = 0.0f;
    if (tid < 8) ((float*)zp)[tid] = 0.0f;
    __syncthreads();

    float* __restrict__ outb = out + b * TT;

    for (int it = 0; it <= TT + 1; ++it) {
        // ---------------- Phase A ----------------
        if (it < TT) {
            // matvec: z[col] = b + x_t*W1[0,col] + sum_m h1[m]*W1[1+m,col]
            float a0 = fmaf(xall[it], w[0], bias);
            float a1 = 0.f, a2 = 0.f, a3 = 0.f;
            const float4* h4p = (const float4*)h1s;
#pragma unroll
            for (int m4 = 0; m4 < 16; ++m4) {
                float4 h4 = h4p[m4];              // uniform addr -> broadcast
                a0 = fmaf(h4.x, w[1 + 4*m4], a0);
                a1 = fmaf(h4.y, w[2 + 4*m4], a1);
                a2 = fmaf(h4.z, w[3 + 4*m4], a2);
                a3 = fmaf(h4.w, w[4 + 4*m4], a3);
            }
            const float acc = (a0 + a1) + (a2 + a3);
            float v;
            if (wave == 0)      v = fsig(acc);          // i
            else if (wave == 1) v = ftanh(acc);         // j
            else if (wave == 2) v = fsig(acc + 1.0f);   // f + forget bias
            else                v = fsig(acc);          // o
            gbuf[wave][lane] = v;
        }
        // layer-2 partial for step (it-1): uses h1s = h1(it-1)
        if (it >= 1 && it <= TT) {
            float p = h1s[lane] * w2g;
#pragma unroll
            for (int s = 1; s < 64; s <<= 1) p += __shfl_xor(p, s, 64);
            if (lane == 0) zp[it & 1][wave] = p;
        }
        // scalar chain for step (it-2): consumes zp written last iteration
        if (wave == 3 && lane == 0 && it >= 2) {
            const int par = (it - 1) & 1;
            float zi = zp[par][0] + fmaf(h2, w2h0, b20);
            float zj = zp[par][1] + fmaf(h2, w2h1, b21);
            float zf = zp[par][2] + fmaf(h2, w2h2, b22);
            float zo = zp[par][3] + fmaf(h2, w2h3, b23);
            c2 = c2 * fsig(zf + 1.0f) + fsig(zi) * ftanh(zj);
            h2 = ftanh(c2) * fsig(zo);
            outb[it - 2] = h2;
        }
        __syncthreads();
        // ---------------- Phase B ----------------
        if (it < TT && wave == 0) {
            c1 = fmaf(c1, gbuf[2][lane], gbuf[0][lane] * gbuf[1][lane]);
            h1s[lane] = ftanh(c1) * gbuf[3][lane];
        }
        __syncthreads();
    }
}

extern "C" void kernel_launch(void* const* d_in, const int* in_sizes, int n_in,
                              void* d_out, int out_size, void* d_ws, size_t ws_size,
                              hipStream_t stream)
{
    const float* x  = (const float*)d_in[0];
    const float* W1 = (const float*)d_in[1];
    const float* b1 = (const float*)d_in[2];
    const float* W2 = (const float*)d_in[3];
    const float* b2 = (const float*)d_in[4];
    float* out = (float*)d_out;
    lstm2_kernel<<<NB, 256, 0, stream>>>(x, W1, b1, W2, b2, out);
}

// Round 2
// 2208.113 us; speedup vs baseline: 1.0801x; 1.0801x over previous
//
#include <hip/hip_runtime.h>

#define TT 2048
#define NB 512

__device__ __forceinline__ float fsig(float x) {
    return 1.0f / (1.0f + __expf(-x));
}
__device__ __forceinline__ float ftanh(float x) {
    return 2.0f / (1.0f + __expf(-2.0f * x)) - 1.0f;
}

// One block (4 waves) per batch element. Wave g owns gate g (TF order i,j,f,o);
// lane u owns hidden unit u. W1 column slice lives in 16 float4 registers.
// c1 state is REDUNDANT per wave (all 4 waves keep identical copies) so the
// gate-combine needs no second barrier; h1 broadcast goes through a
// wave-PRIVATE LDS row (wave-synchronous write->read, no barrier).
// Gate buffer is parity-double-buffered => exactly ONE __syncthreads per step.
// Layer 2 (H2=1) partials via 6-step butterfly, 1-step lagged; scalar (c2,h2)
// chain consumes them one barrier later.
__global__ __launch_bounds__(256, 2)
void lstm2_kernel(const float* __restrict__ x,
                  const float* __restrict__ W1,
                  const float* __restrict__ b1,
                  const float* __restrict__ W2,
                  const float* __restrict__ b2,
                  float* __restrict__ out)
{
    __shared__ __align__(16) float xall[TT];        // 8 KB input row
    __shared__ __align__(16) float h1b[4][64];      // per-wave private h1 bcast
    __shared__ __align__(16) float gbuf[2][4][64];  // parity-dbuf gate values
    __shared__ float zp[2][4];                      // layer-2 partials, parity dbuf

    const int tid  = threadIdx.x;
    const int wave = tid >> 6;
    const int lane = tid & 63;
    const int b    = blockIdx.x;

    for (int i = tid; i < TT; i += 256) xall[i] = x[b * TT + i];

    // W1 is (65, 256) row-major; this wave's gate slice column = wave*64+lane.
    const int col = (wave << 6) + lane;
    float4 w4[16];                       // rows 1..64 (h-part), 64 VGPRs
#pragma unroll
    for (int r4 = 0; r4 < 16; ++r4) {
        w4[r4].x = W1[(4 * r4 + 1) * 256 + col];
        w4[r4].y = W1[(4 * r4 + 2) * 256 + col];
        w4[r4].z = W1[(4 * r4 + 3) * 256 + col];
        w4[r4].w = W1[(4 * r4 + 4) * 256 + col];
    }
    const float w0x  = W1[col];          // row 0 (x-part)
    const float bias = b1[col];
    const float w2g  = W2[lane * 4 + wave];  // W2 (65,4) row-major, h1-part

    // scalar-chain weights (loaded by all lanes; only wave3/lane0 uses them)
    const float w2h0 = W2[256], w2h1 = W2[257], w2h2 = W2[258], w2h3 = W2[259];
    const float b20 = b2[0], b21 = b2[1], b22 = b2[2], b23 = b2[3];

    float c1 = 0.0f;             // redundant copy per wave, unit = lane
    float c2 = 0.0f, h2 = 0.0f;  // layer-2 scalar state (wave3/lane0)

    h1b[wave][lane] = 0.0f;
    if (tid < 8) ((float*)zp)[tid] = 0.0f;
    __syncthreads();

    float* __restrict__ outb = out + b * TT;

    for (int it = 0; it <= TT; ++it) {
        const int p = it & 1;
        // ---- Phase A: matvec for step `it` using h1(it-1) from own bcast row
        if (it < TT) {
            float a0 = fmaf(xall[it], w0x, bias);
            float a1 = 0.f, a2 = 0.f, a3 = 0.f;
            const float4* __restrict__ h4 = (const float4*)h1b[wave];
#pragma unroll
            for (int m = 0; m < 16; ++m) {
                float4 h = h4[m];                 // uniform addr -> broadcast
                a0 = fmaf(h.x, w4[m].x, a0);
                a1 = fmaf(h.y, w4[m].y, a1);
                a2 = fmaf(h.z, w4[m].z, a2);
                a3 = fmaf(h.w, w4[m].w, a3);
            }
            const float acc = (a0 + a1) + (a2 + a3);
            float v;
            if (wave == 1)      v = ftanh(acc);         // j
            else if (wave == 2) v = fsig(acc + 1.0f);   // f + forget bias
            else                v = fsig(acc);          // i, o
            gbuf[p][wave][lane] = v;
        }
        __syncthreads();   // the ONLY barrier per step
        // ---- Phase B: every wave redundantly combines gates -> c1, h1(it)
        if (it < TT) {
            const float gi = gbuf[p][0][lane];
            const float gj = gbuf[p][1][lane];
            const float gf = gbuf[p][2][lane];
            const float go = gbuf[p][3][lane];
            c1 = fmaf(c1, gf, gi * gj);
            const float h1 = ftanh(c1) * go;
            h1b[wave][lane] = h1;          // wave-private row, no barrier needed
            // layer-2 partial for step `it`: wave g reduces h1 . W2[:,g]
            float pr = h1 * w2g;
#pragma unroll
            for (int s = 1; s < 64; s <<= 1) pr += __shfl_xor(pr, s, 64);
            if (lane == 0) zp[p][wave] = pr;
        }
        // ---- scalar chain for step it-1 (partials crossed barrier(it))
        if (wave == 3 && lane == 0 && it >= 1) {
            const int q = (it - 1) & 1;
            const float zi = zp[q][0] + fmaf(h2, w2h0, b20);
            const float zj = zp[q][1] + fmaf(h2, w2h1, b21);
            const float zf = zp[q][2] + fmaf(h2, w2h2, b22);
            const float zo = zp[q][3] + fmaf(h2, w2h3, b23);
            c2 = c2 * fsig(zf + 1.0f) + fsig(zi) * ftanh(zj);
            h2 = ftanh(c2) * fsig(zo);
            outb[it - 1] = h2;
        }
    }
}

extern "C" void kernel_launch(void* const* d_in, const int* in_sizes, int n_in,
                              void* d_out, int out_size, void* d_ws, size_t ws_size,
                              hipStream_t stream)
{
    const float* x  = (const float*)d_in[0];
    const float* W1 = (const float*)d_in[1];
    const float* b1 = (const float*)d_in[2];
    const float* W2 = (const float*)d_in[3];
    const float* b2 = (const float*)d_in[4];
    float* out = (float*)d_out;
    lstm2_kernel<<<NB, 256, 0, stream>>>(x, W1, b1, W2, b2, out);
}

// Round 3
// 2200.686 us; speedup vs baseline: 1.0838x; 1.0034x over previous
//
#include <hip/hip_runtime.h>

#define TT 2048
#define NB 512

__device__ __forceinline__ float fsig(float x) {
    return 1.0f / (1.0f + __expf(-x));
}
__device__ __forceinline__ float ftanh(float x) {
    return 2.0f / (1.0f + __expf(-2.0f * x)) - 1.0f;
}

// One block (4 waves) per batch element. Wave g owns gate g (TF order i,j,f,o);
// lane u owns hidden unit u. The 64 h-part W1 weights are 64 INDIVIDUALLY
// NAMED scalar registers (macro-expanded) — arrays failed SROA in R1/R2
// (VGPR_Count 52/56 proved weights were reloaded from L2 every step).
// c1 state is redundant per wave; h1 broadcast via wave-private LDS row;
// gate buffer parity-double-buffered => ONE __syncthreads per step.
// Layer 2 (H2=1): butterfly partials 1-step lagged, scalar chain consumes
// them one barrier later.
__global__ __launch_bounds__(256, 2)
void lstm2_kernel(const float* __restrict__ x,
                  const float* __restrict__ W1,
                  const float* __restrict__ b1,
                  const float* __restrict__ W2,
                  const float* __restrict__ b2,
                  float* __restrict__ out)
{
    __shared__ __align__(16) float xall[TT];        // 8 KB input row
    __shared__ __align__(16) float h1b[4][64];      // per-wave private h1 bcast
    __shared__ __align__(16) float gbuf[2][4][64];  // parity-dbuf gate values
    __shared__ float zp[2][4];                      // layer-2 partials

    const int tid  = threadIdx.x;
    const int wave = tid >> 6;
    const int lane = tid & 63;
    const int b    = blockIdx.x;

    for (int i = tid; i < TT; i += 256) xall[i] = x[b * TT + i];

    // W1 is (65, 256) row-major; this wave's gate column = wave*64 + lane.
    const int col = (wave << 6) + lane;

    // 64 named scalar weight registers (rows 1..64 = h-part of W1 column).
#define DECLW(q) \
    const float wx##q = W1[(4*(q)+1)*256 + col]; \
    const float wy##q = W1[(4*(q)+2)*256 + col]; \
    const float wz##q = W1[(4*(q)+3)*256 + col]; \
    const float ww##q = W1[(4*(q)+4)*256 + col];
    DECLW(0)  DECLW(1)  DECLW(2)  DECLW(3)
    DECLW(4)  DECLW(5)  DECLW(6)  DECLW(7)
    DECLW(8)  DECLW(9)  DECLW(10) DECLW(11)
    DECLW(12) DECLW(13) DECLW(14) DECLW(15)
#undef DECLW

    const float w0x  = W1[col];              // row 0 (x-part)
    const float bias = b1[col];
    const float w2g  = W2[lane * 4 + wave];  // W2 (65,4) row-major, h1-part

    // scalar-chain constants (used only by wave3/lane0)
    const float w2h0 = W2[256], w2h1 = W2[257], w2h2 = W2[258], w2h3 = W2[259];
    const float b20 = b2[0], b21 = b2[1], b22 = b2[2], b23 = b2[3];

    float c1 = 0.0f;             // redundant per wave, unit = lane
    float c2 = 0.0f, h2 = 0.0f;  // layer-2 scalar state (wave3/lane0)

    h1b[wave][lane] = 0.0f;
    if (tid < 8) ((float*)zp)[tid] = 0.0f;
    __syncthreads();

    float* __restrict__ outb = out + b * TT;

    for (int it = 0; it <= TT; ++it) {
        const int p = it & 1;
        // ---- Phase A: matvec for step `it` using h1(it-1) from own bcast row
        if (it < TT) {
            const float* hr = h1b[wave];     // shared addrspace, broadcast reads
            float a0 = fmaf(xall[it], w0x, bias);
            float a1 = 0.f, a2 = 0.f, a3 = 0.f;
#define FMA4(q) \
            a0 = fmaf(hr[4*(q)+0], wx##q, a0); \
            a1 = fmaf(hr[4*(q)+1], wy##q, a1); \
            a2 = fmaf(hr[4*(q)+2], wz##q, a2); \
            a3 = fmaf(hr[4*(q)+3], ww##q, a3);
            FMA4(0)  FMA4(1)  FMA4(2)  FMA4(3)
            FMA4(4)  FMA4(5)  FMA4(6)  FMA4(7)
            FMA4(8)  FMA4(9)  FMA4(10) FMA4(11)
            FMA4(12) FMA4(13) FMA4(14) FMA4(15)
#undef FMA4
            const float acc = (a0 + a1) + (a2 + a3);
            float v;
            if (wave == 1)      v = ftanh(acc);         // j
            else if (wave == 2) v = fsig(acc + 1.0f);   // f + forget bias
            else                v = fsig(acc);          // i, o
            gbuf[p][wave][lane] = v;
        }
        __syncthreads();   // the ONLY barrier per step
        // ---- Phase B: every wave redundantly combines gates -> c1, h1(it)
        if (it < TT) {
            const float gi = gbuf[p][0][lane];
            const float gj = gbuf[p][1][lane];
            const float gf = gbuf[p][2][lane];
            const float go = gbuf[p][3][lane];
            c1 = fmaf(c1, gf, gi * gj);
            const float h1 = ftanh(c1) * go;
            h1b[wave][lane] = h1;          // wave-private row, no barrier needed
            // layer-2 partial for step `it`: wave g reduces h1 . W2[:,g]
            float pr = h1 * w2g;
#pragma unroll
            for (int s = 1; s < 64; s <<= 1) pr += __shfl_xor(pr, s, 64);
            if (lane == 0) zp[p][wave] = pr;
        }
        // ---- scalar chain for step it-1 (partials crossed barrier(it))
        if (wave == 3 && lane == 0 && it >= 1) {
            const int q = (it - 1) & 1;
            const float zi = zp[q][0] + fmaf(h2, w2h0, b20);
            const float zj = zp[q][1] + fmaf(h2, w2h1, b21);
            const float zf = zp[q][2] + fmaf(h2, w2h2, b22);
            const float zo = zp[q][3] + fmaf(h2, w2h3, b23);
            c2 = c2 * fsig(zf + 1.0f) + fsig(zi) * ftanh(zj);
            h2 = ftanh(c2) * fsig(zo);
            outb[it - 1] = h2;
        }
    }
}

extern "C" void kernel_launch(void* const* d_in, const int* in_sizes, int n_in,
                              void* d_out, int out_size, void* d_ws, size_t ws_size,
                              hipStream_t stream)
{
    const float* x  = (const float*)d_in[0];
    const float* W1 = (const float*)d_in[1];
    const float* b1 = (const float*)d_in[2];
    const float* W2 = (const float*)d_in[3];
    const float* b2 = (const float*)d_in[4];
    float* out = (float*)d_out;
    lstm2_kernel<<<NB, 256, 0, stream>>>(x, W1, b1, W2, b2, out);
}

// Round 4
// 2194.969 us; speedup vs baseline: 1.0866x; 1.0026x over previous
//
#include <hip/hip_runtime.h>

#define TT 2048
#define NB 512

__device__ __forceinline__ float fsig(float x) {
    return 1.0f / (1.0f + __expf(-x));
}
__device__ __forceinline__ float ftanh(float x) {
    return 2.0f / (1.0f + __expf(-2.0f * x)) - 1.0f;
}

// One block (4 waves) per batch element. Wave g owns gate g (TF order i,j,f,o);
// lane u owns hidden unit u. 64 h-part W1 weights as named scalars.
// KEY FIX vs R3: amdgpu_waves_per_eu(2,2) — without it the backend targets
// 8 waves/EU (<=64 VGPR) and REMATERIALIZES the invariant weight loads into
// the loop (VGPR_Count stayed 52 across R1-R3; ~190 excess VALU/step from
// per-step reload address math). Grid gives only 2 blocks/CU anyway, so
// clamping to 2 waves/EU costs nothing and raises the VGPR budget to 256.
// c1 redundant per wave; h1 bcast via wave-private LDS row; gate buffer
// parity-dbuf => ONE __syncthreads per step. Layer 2 lagged as before.
__global__ __launch_bounds__(256)
__attribute__((amdgpu_waves_per_eu(2, 2)))
void lstm2_kernel(const float* __restrict__ x,
                  const float* __restrict__ W1,
                  const float* __restrict__ b1,
                  const float* __restrict__ W2,
                  const float* __restrict__ b2,
                  float* __restrict__ out)
{
    __shared__ __align__(16) float xall[TT];        // 8 KB input row
    __shared__ __align__(16) float h1b[4][64];      // per-wave private h1 bcast
    __shared__ __align__(16) float gbuf[2][4][64];  // parity-dbuf gate values
    __shared__ float zp[2][4];                      // layer-2 partials

    const int tid  = threadIdx.x;
    const int wave = tid >> 6;
    const int lane = tid & 63;
    const int b    = blockIdx.x;

    for (int i = tid; i < TT; i += 256) xall[i] = x[b * TT + i];

    // W1 is (65, 256) row-major; this wave's gate column = wave*64 + lane.
    const int col = (wave << 6) + lane;

    // 64 named scalar weight registers (rows 1..64 = h-part of W1 column).
#define DECLW(q) \
    const float wx##q = W1[(4*(q)+1)*256 + col]; \
    const float wy##q = W1[(4*(q)+2)*256 + col]; \
    const float wz##q = W1[(4*(q)+3)*256 + col]; \
    const float ww##q = W1[(4*(q)+4)*256 + col];
    DECLW(0)  DECLW(1)  DECLW(2)  DECLW(3)
    DECLW(4)  DECLW(5)  DECLW(6)  DECLW(7)
    DECLW(8)  DECLW(9)  DECLW(10) DECLW(11)
    DECLW(12) DECLW(13) DECLW(14) DECLW(15)
#undef DECLW

    const float w0x  = W1[col];              // row 0 (x-part)
    const float bias = b1[col];
    const float w2g  = W2[lane * 4 + wave];  // W2 (65,4) row-major, h1-part

    // scalar-chain constants (used only by wave3/lane0)
    const float w2h0 = W2[256], w2h1 = W2[257], w2h2 = W2[258], w2h3 = W2[259];
    const float b20 = b2[0], b21 = b2[1], b22 = b2[2], b23 = b2[3];

    float c1 = 0.0f;             // redundant per wave, unit = lane
    float c2 = 0.0f, h2 = 0.0f;  // layer-2 scalar state (wave3/lane0)

    h1b[wave][lane] = 0.0f;
    if (tid < 8) ((float*)zp)[tid] = 0.0f;
    __syncthreads();

    float* __restrict__ outb = out + b * TT;

    for (int it = 0; it <= TT; ++it) {
        const int p = it & 1;
        // ---- Phase A: matvec for step `it` using h1(it-1) from own bcast row
        if (it < TT) {
            const float* hr = h1b[wave];     // shared addrspace, broadcast reads
            float a0 = fmaf(xall[it], w0x, bias);
            float a1 = 0.f, a2 = 0.f, a3 = 0.f;
#define FMA4(q) \
            a0 = fmaf(hr[4*(q)+0], wx##q, a0); \
            a1 = fmaf(hr[4*(q)+1], wy##q, a1); \
            a2 = fmaf(hr[4*(q)+2], wz##q, a2); \
            a3 = fmaf(hr[4*(q)+3], ww##q, a3);
            FMA4(0)  FMA4(1)  FMA4(2)  FMA4(3)
            FMA4(4)  FMA4(5)  FMA4(6)  FMA4(7)
            FMA4(8)  FMA4(9)  FMA4(10) FMA4(11)
            FMA4(12) FMA4(13) FMA4(14) FMA4(15)
#undef FMA4
            const float acc = (a0 + a1) + (a2 + a3);
            float v;
            if (wave == 1)      v = ftanh(acc);         // j
            else if (wave == 2) v = fsig(acc + 1.0f);   // f + forget bias
            else                v = fsig(acc);          // i, o
            gbuf[p][wave][lane] = v;
        }
        __syncthreads();   // the ONLY barrier per step
        // ---- Phase B: every wave redundantly combines gates -> c1, h1(it)
        if (it < TT) {
            const float gi = gbuf[p][0][lane];
            const float gj = gbuf[p][1][lane];
            const float gf = gbuf[p][2][lane];
            const float go = gbuf[p][3][lane];
            c1 = fmaf(c1, gf, gi * gj);
            const float h1 = ftanh(c1) * go;
            h1b[wave][lane] = h1;          // wave-private row, no barrier needed
            // layer-2 partial for step `it`: wave g reduces h1 . W2[:,g]
            float pr = h1 * w2g;
#pragma unroll
            for (int s = 1; s < 64; s <<= 1) pr += __shfl_xor(pr, s, 64);
            if (lane == 0) zp[p][wave] = pr;
        }
        // ---- scalar chain for step it-1 (partials crossed barrier(it))
        if (wave == 3 && lane == 0 && it >= 1) {
            const int q = (it - 1) & 1;
            const float zi = zp[q][0] + fmaf(h2, w2h0, b20);
            const float zj = zp[q][1] + fmaf(h2, w2h1, b21);
            const float zf = zp[q][2] + fmaf(h2, w2h2, b22);
            const float zo = zp[q][3] + fmaf(h2, w2h3, b23);
            c2 = c2 * fsig(zf + 1.0f) + fsig(zi) * ftanh(zj);
            h2 = ftanh(c2) * fsig(zo);
            outb[it - 1] = h2;
        }
    }
}

extern "C" void kernel_launch(void* const* d_in, const int* in_sizes, int n_in,
                              void* d_out, int out_size, void* d_ws, size_t ws_size,
                              hipStream_t stream)
{
    const float* x  = (const float*)d_in[0];
    const float* W1 = (const float*)d_in[1];
    const float* b1 = (const float*)d_in[2];
    const float* W2 = (const float*)d_in[3];
    const float* b2 = (const float*)d_in[4];
    float* out = (float*)d_out;
    lstm2_kernel<<<NB, 256, 0, stream>>>(x, W1, b1, W2, b2, out);
}